// Round 4
// baseline (1463.328 us; speedup 1.0000x reference)
//
#include <hip/hip_runtime.h>

// Round 4: round-2 structure at 2 co-resident blocks/CU.
// 512 blocks x 512 threads, 4 batch rows/block -> 2 blocks per CU whose
// independent barriers de-phase, overlapping one block's MFMA with the
// other's elementwise/waits (the r1-r3 kernels were 1 phase-locked
// block/CU => per-step cost was the SUM of phases).
// Gate GEMM: M=16 slots (4 real + 12 garbage-tolerant pad), N=512 gates
// (wave w owns H-cols 16w..16w+15, all 4 gates => gates in-register),
// K=192. Weights register-resident (96 VGPR). A=[x|h] in LDS frag-order,
// double-buffered, ONE barrier/step. Elementwise: quad-spread via shfl
// -> 1 cell/lane, c in 1 register. __launch_bounds__(512,4) caps VGPR
// at 128 so 4 waves/SIMD (2 blocks) fit.

#define Bsz   2048
#define Tlen  256
#define Fdim  64
#define Hdim  128
#define ROWS  4
#define NTH   512
#define TILE_E 512            // elems per kt tile (64 lanes x 8)
#define NKT   6               // kt 0,1 = x (K 0..63), kt 2..5 = h (K 64..191)
#define BUF_E (NKT * TILE_E)  // 3072 bf16 = 6 KB per buffer

using bf16x8 = __attribute__((ext_vector_type(8))) __bf16;
using f32x4  = __attribute__((ext_vector_type(4))) float;

__device__ __forceinline__ float fast_rcp(float x) {
#if __has_builtin(__builtin_amdgcn_rcpf)
    return __builtin_amdgcn_rcpf(x);
#else
    return 1.0f / x;
#endif
}
__device__ __forceinline__ float fast_exp2(float x) {
#if __has_builtin(__builtin_amdgcn_exp2f)
    return __builtin_amdgcn_exp2f(x);
#else
    return exp2f(x);
#endif
}
__device__ __forceinline__ float fsig(float x) {
    return fast_rcp(1.0f + fast_exp2(-1.4426950408889634f * x));
}
__device__ __forceinline__ float ftanh(float x) {
    float e = fast_exp2(-2.8853900817779268f * x);   // exp(-2x)
    return (1.0f - e) * fast_rcp(1.0f + e);
}

// frag-order elem index for logical A[row][k]
__device__ __forceinline__ int frag_elem(int row, int k) {
    return (k >> 5) * TILE_E + ((((k >> 3) & 3) * 16 + row) * 8) + (k & 7);
}

__global__ __launch_bounds__(NTH, 4)
void lstm_fused(const float* __restrict__ x,
                const float* __restrict__ W_ih,
                const float* __restrict__ W_hh,
                const float* __restrict__ b_ih,
                const float* __restrict__ b_hh,
                const float* __restrict__ W1,
                const float* __restrict__ b1,
                const float* __restrict__ W2,
                const float* __restrict__ b2,
                float* __restrict__ out)
{
    __shared__ __bf16 Abuf[2][BUF_E];      // 12 KB, fragment-order A operand
    __shared__ float  hlast[ROWS * Hdim];  // 2 KB fp32 h_T for head
    __shared__ float  zbuf[ROWS * 32];

    const int tid  = threadIdx.x;
    const int w    = tid >> 6;
    const int lane = tid & 63;
    const int quad = lane >> 4;
    const int l16  = lane & 15;
    const int b0   = blockIdx.x * ROWS;

    // ---- B fragments: 6 kt x 4 gates, register-resident (96 VGPR) ----
    // lane holds B[k = kt*32 + quad*8 + j][n = g*128 + w*16 + l16]
    bf16x8 bw[NKT][4];
    #pragma unroll
    for (int kt = 0; kt < NKT; ++kt) {
        const int k0 = kt * 32 + quad * 8;
        #pragma unroll
        for (int g = 0; g < 4; ++g) {
            const int n = g * Hdim + w * 16 + l16;
            const float* p = (kt < 2) ? (W_ih + (size_t)n * Fdim + k0)
                                      : (W_hh + (size_t)n * Hdim + (k0 - Fdim));
            float4 lo = *(const float4*)p;
            float4 hi = *(const float4*)(p + 4);
            bf16x8 r;
            r[0]=(__bf16)lo.x; r[1]=(__bf16)lo.y; r[2]=(__bf16)lo.z; r[3]=(__bf16)lo.w;
            r[4]=(__bf16)hi.x; r[5]=(__bf16)hi.y; r[6]=(__bf16)hi.z; r[7]=(__bf16)hi.w;
            bw[kt][g] = r;
        }
    }
    float biasv[4];
    #pragma unroll
    for (int g = 0; g < 4; ++g) {
        const int n = g * Hdim + w * 16 + l16;
        biasv[g] = b_ih[n] + b_hh[n];
    }

    // ---- x staging: threads 0..127 -> (row = tid>>5, feat pair fp) ----
    const bool sx_on  = tid < 128;
    const int  sx_row = (tid >> 5) & 3;
    const int  sx_fp  = tid & 31;
    const int  f0     = 2 * sx_fp;
    const float* xrp  = x + (size_t)(b0 + sx_row) * (Tlen * Fdim) + f0;
    const int sx_elem = frag_elem(sx_row, f0);   // f0&7 even -> 4B aligned

    // ---- elementwise cell: (slot = quad, hc = 16w + l16) ----
    const int hc     = 16 * w + l16;
    const int h_elem = frag_elem(quad, Fdim + hc);

    // ---- init: zero h-region of buf0 (h0 = 0); pad rows stay garbage ----
    {
        const int r_ = tid >> 7;          // 0..3
        const int hk = tid & 127;
        Abuf[0][frag_elem(r_, Fdim + hk)] = (__bf16)0.0f;
    }
    float2 xpre = make_float2(0.f, 0.f);
    if (sx_on) {
        float2 v0 = *(const float2*)xrp;              // x_0
        __bf16 a0[2] = {(__bf16)v0.x, (__bf16)v0.y};
        *(uint*)&Abuf[0][sx_elem] = *(uint*)a0;
        xpre = *(const float2*)(xrp + Fdim);          // x_1 -> stored in step 0
    }
    __syncthreads();

    float cst = 0.0f;

    for (int t = 0; t < Tlen; ++t) {
        const int p = t & 1;
        const __bf16* rb = Abuf[p];
        __bf16*      wbf = (__bf16*)Abuf[1 - p];

        // A fragments: conflict-free ds_read_b128 at lane*16B
        bf16x8 af[NKT];
        #pragma unroll
        for (int kt = 0; kt < NKT; ++kt)
            af[kt] = *(const bf16x8*)&rb[kt * TILE_E + lane * 8];

        // prefetch x_{t+2} (stored next iteration)
        float2 xnext = make_float2(0.f, 0.f);
        if (sx_on && (t + 2) < Tlen)
            xnext = *(const float2*)(xrp + (size_t)(t + 2) * Fdim);

        // 24 MFMA: 4 independent gate chains x 6 kt
        f32x4 acc[4];
        #pragma unroll
        for (int g = 0; g < 4; ++g)
            acc[g] = (f32x4){biasv[g], biasv[g], biasv[g], biasv[g]};
        #pragma unroll
        for (int kt = 0; kt < NKT; ++kt) {
            #pragma unroll
            for (int g = 0; g < 4; ++g)
                acc[g] = __builtin_amdgcn_mfma_f32_16x16x32_bf16(af[kt], bw[kt][g], acc[g], 0, 0, 0);
        }

        // quad-spread: real cells live in quad-0 lanes' acc[g][r=0..3]
        // (slot = r). Lane (quad,l16) pulls acc[g][quad] from lane (0,l16).
        float ga[4];
        #pragma unroll
        for (int g = 0; g < 4; ++g) {
            float t0 = __shfl(acc[g][0], l16);
            float t1 = __shfl(acc[g][1], l16);
            float t2 = __shfl(acc[g][2], l16);
            float t3 = __shfl(acc[g][3], l16);
            float s01 = (quad & 1) ? t1 : t0;
            float s23 = (quad & 1) ? t3 : t2;
            ga[g] = (quad & 2) ? s23 : s01;
        }

        // elementwise: ONE cell per lane, c in a register
        {
            float iv = fsig(ga[0]);
            float fv = fsig(ga[1]);
            float gv = ftanh(ga[2]);
            float ov = fsig(ga[3]);
            cst = fv * cst + iv * gv;
            float h = ov * ftanh(cst);
            wbf[h_elem] = (__bf16)h;
            if (t == Tlen - 1) hlast[quad * Hdim + hc] = h;
        }

        // stage x_{t+1} (held in xpre) into the write buffer
        if (sx_on && (t + 1) < Tlen) {
            __bf16 xa[2] = {(__bf16)xpre.x, (__bf16)xpre.y};
            *(uint*)&wbf[sx_elem] = *(uint*)xa;
        }
        xpre = xnext;
        __syncthreads();   // the ONLY barrier per step
    }

    // ---- head: z = relu(h @ W1^T + b1); out = sigmoid(z @ W2^T + b2) ----
    if (tid < ROWS * 32) {
        const int b = tid >> 5, n = tid & 31;
        const float4* w4 = (const float4*)(W1 + n * Hdim);
        const float4* h4 = (const float4*)(hlast + b * Hdim);
        float s = b1[n];
        #pragma unroll
        for (int kk = 0; kk < Hdim / 4; ++kk) {
            float4 wv = w4[kk];
            float4 hv = h4[kk];
            s += wv.x * hv.x + wv.y * hv.y + wv.z * hv.z + wv.w * hv.w;
        }
        zbuf[b * 32 + n] = fmaxf(s, 0.0f);
    }
    __syncthreads();
    if (tid < ROWS) {
        float s = b2[0];
        #pragma unroll
        for (int n = 0; n < 32; ++n) s += zbuf[tid * 32 + n] * W2[n];
        out[b0 + tid] = fsig(s);
    }
}

extern "C" void kernel_launch(void* const* d_in, const int* in_sizes, int n_in,
                              void* d_out, int out_size, void* d_ws, size_t ws_size,
                              hipStream_t stream) {
    const float* x    = (const float*)d_in[0];
    const float* W_ih = (const float*)d_in[1];
    const float* W_hh = (const float*)d_in[2];
    const float* b_ih = (const float*)d_in[3];
    const float* b_hh = (const float*)d_in[4];
    const float* W1   = (const float*)d_in[5];
    const float* b1   = (const float*)d_in[6];
    const float* W2   = (const float*)d_in[7];
    const float* b2   = (const float*)d_in[8];
    float* out = (float*)d_out;

    dim3 grid(Bsz / ROWS), block(NTH);
    lstm_fused<<<grid, block, 0, stream>>>(x, W_ih, W_hh, b_ih, b_hh, W1, b1, W2, b2, out);
}

// Round 5
// 376.048 us; speedup vs baseline: 3.8913x; 3.8913x over previous
//
#include <hip/hip_runtime.h>

// Round 5: r2 structure + row-duplicated A operand (no shfl).
// 256 blocks x 512 threads, 8 batch rows/block, bf16 MFMA 16x16x32.
// A operand [x|h] stores each batch row TWICE (frag-row r = batch row r&7):
// the half of the M=16 tile that was padding now computes duplicate gates,
// so every lane's C/D accumulators hold valid cells -> elementwise is
// 2 cells/lane with NO cross-lane ops (r2's 16 ds_bpermute/wave = ~770
// serial LDS cyc/step are gone). Weights register-resident (96 VGPR),
// gates in-register (wave w owns H-cols 16w..16w+15, all 4 gates),
// frag-order LDS A double-buffered, ONE barrier/step.

#define Bsz   2048
#define Tlen  256
#define Fdim  64
#define Hdim  128
#define ROWS  8
#define NTH   512
#define TILE_E 512            // elems per kt tile (64 lanes x 8)
#define NKT   6               // kt 0,1 = x (K 0..63), kt 2..5 = h (K 64..191)
#define BUF_E (NKT * TILE_E)  // 3072 bf16 = 6 KB per buffer

using bf16x8 = __attribute__((ext_vector_type(8))) __bf16;
using f32x4  = __attribute__((ext_vector_type(4))) float;

__device__ __forceinline__ float fast_rcp(float x) {
#if __has_builtin(__builtin_amdgcn_rcpf)
    return __builtin_amdgcn_rcpf(x);
#else
    return 1.0f / x;
#endif
}
__device__ __forceinline__ float fast_exp2(float x) {
#if __has_builtin(__builtin_amdgcn_exp2f)
    return __builtin_amdgcn_exp2f(x);
#else
    return exp2f(x);
#endif
}
__device__ __forceinline__ float fsig(float x) {
    return fast_rcp(1.0f + fast_exp2(-1.4426950408889634f * x));
}
__device__ __forceinline__ float ftanh(float x) {
    float e = fast_exp2(-2.8853900817779268f * x);   // exp(-2x)
    return (1.0f - e) * fast_rcp(1.0f + e);
}

// frag-order elem index for logical A[frag_row][k]
__device__ __forceinline__ int frag_elem(int row, int k) {
    return (k >> 5) * TILE_E + ((((k >> 3) & 3) * 16 + row) * 8) + (k & 7);
}

__global__ __launch_bounds__(NTH, 2)
void lstm_fused(const float* __restrict__ x,
                const float* __restrict__ W_ih,
                const float* __restrict__ W_hh,
                const float* __restrict__ b_ih,
                const float* __restrict__ b_hh,
                const float* __restrict__ W1,
                const float* __restrict__ b1,
                const float* __restrict__ W2,
                const float* __restrict__ b2,
                float* __restrict__ out)
{
    __shared__ __bf16 Abuf[2][BUF_E];       // 12 KB, fragment-order A operand
    __shared__ float  hlast[ROWS * Hdim];   // 4 KB fp32 h_T for head
    __shared__ float  zbuf[ROWS * 32];

    const int tid  = threadIdx.x;
    const int w    = tid >> 6;
    const int lane = tid & 63;
    const int quad = lane >> 4;
    const int l16  = lane & 15;
    const int b0   = blockIdx.x * ROWS;

    // ---- B fragments: 6 kt x 4 gates, register-resident (96 VGPR) ----
    // lane holds B[k = kt*32 + quad*8 + j][n = g*128 + w*16 + l16]
    bf16x8 bw[NKT][4];
    #pragma unroll
    for (int kt = 0; kt < NKT; ++kt) {
        const int k0 = kt * 32 + quad * 8;
        #pragma unroll
        for (int g = 0; g < 4; ++g) {
            const int n = g * Hdim + w * 16 + l16;
            const float* p = (kt < 2) ? (W_ih + (size_t)n * Fdim + k0)
                                      : (W_hh + (size_t)n * Hdim + (k0 - Fdim));
            float4 lo = *(const float4*)p;
            float4 hi = *(const float4*)(p + 4);
            bf16x8 r;
            r[0]=(__bf16)lo.x; r[1]=(__bf16)lo.y; r[2]=(__bf16)lo.z; r[3]=(__bf16)lo.w;
            r[4]=(__bf16)hi.x; r[5]=(__bf16)hi.y; r[6]=(__bf16)hi.z; r[7]=(__bf16)hi.w;
            bw[kt][g] = r;
        }
    }
    float biasv[4];
    #pragma unroll
    for (int g = 0; g < 4; ++g) {
        const int n = g * Hdim + w * 16 + l16;
        biasv[g] = b_ih[n] + b_hh[n];
    }

    // ---- x staging: threads 0..255 -> (row = tid&7, feat pair fp) ----
    // each staged value written to frag rows row AND row+8 (duplication)
    const bool sx_on  = tid < 256;
    const int  sx_row = tid & 7;
    const int  sx_fp  = (tid >> 3) & 31;
    const int  f0     = 2 * sx_fp;
    const float* xrp  = x + (size_t)(b0 + sx_row) * (Tlen * Fdim) + f0;
    const int sx_e0 = frag_elem(sx_row,     f0);   // f0 even -> 4B aligned
    const int sx_e1 = frag_elem(sx_row + 8, f0);

    // ---- elementwise cells: lane (quad,l16), wave w ----
    // r0 = 2*(quad>>1); cell s (s=0,1): acc[g][r0+s], batch row (quad&1)*4+r0+s
    const int r0  = (quad >> 1) * 2;
    const int brb = (quad & 1) * 4 + r0;     // batch row of cell s=0
    const int hc  = 16 * w + l16;            // H-col 0..127
    const int h_e0a = frag_elem(brb,     Fdim + hc);
    const int h_e0b = frag_elem(brb + 8, Fdim + hc);
    const int h_e1a = frag_elem(brb + 1,     Fdim + hc);
    const int h_e1b = frag_elem(brb + 1 + 8, Fdim + hc);

    // ---- init: zero buf0 (h0 = 0 everywhere), stage x_0 (both copies) ----
    #pragma unroll
    for (int i = 0; i < BUF_E / NTH; ++i)
        Abuf[0][tid + i * NTH] = (__bf16)0.0f;
    float2 xpre = make_float2(0.f, 0.f);
    __syncthreads();
    if (sx_on) {
        float2 v0 = *(const float2*)xrp;              // x_0
        __bf16 a0[2] = {(__bf16)v0.x, (__bf16)v0.y};
        *(uint*)&Abuf[0][sx_e0] = *(uint*)a0;
        *(uint*)&Abuf[0][sx_e1] = *(uint*)a0;
        xpre = *(const float2*)(xrp + Fdim);          // x_1 -> stored in step 0
    }
    __syncthreads();

    float cc0 = 0.0f, cc1 = 0.0f;

    for (int t = 0; t < Tlen; ++t) {
        const int p = t & 1;
        const __bf16* rb = Abuf[p];
        __bf16*      wbf = (__bf16*)Abuf[1 - p];

        // A fragments: conflict-free ds_read_b128 at lane*16B
        bf16x8 af[NKT];
        #pragma unroll
        for (int kt = 0; kt < NKT; ++kt)
            af[kt] = *(const bf16x8*)&rb[kt * TILE_E + lane * 8];

        // prefetch x_{t+2} (stored next iteration)
        float2 xnext = make_float2(0.f, 0.f);
        if (sx_on && (t + 2) < Tlen)
            xnext = *(const float2*)(xrp + (size_t)(t + 2) * Fdim);

        // 24 MFMA: 4 independent gate chains x 6 kt
        f32x4 acc[4];
        #pragma unroll
        for (int g = 0; g < 4; ++g)
            acc[g] = (f32x4){biasv[g], biasv[g], biasv[g], biasv[g]};
        #pragma unroll
        for (int kt = 0; kt < NKT; ++kt) {
            #pragma unroll
            for (int g = 0; g < 4; ++g)
                acc[g] = __builtin_amdgcn_mfma_f32_16x16x32_bf16(af[kt], bw[kt][g], acc[g], 0, 0, 0);
        }

        // elementwise: 2 cells/lane straight from acc (no cross-lane ops)
        {
            float iv = fsig(acc[0][r0]);
            float fv = fsig(acc[1][r0]);
            float gv = ftanh(acc[2][r0]);
            float ov = fsig(acc[3][r0]);
            cc0 = fv * cc0 + iv * gv;
            float h = ov * ftanh(cc0);
            __bf16 hb = (__bf16)h;
            wbf[h_e0a] = hb;
            wbf[h_e0b] = hb;
            if (t == Tlen - 1) hlast[brb * Hdim + hc] = h;
        }
        {
            float iv = fsig(acc[0][r0 + 1]);
            float fv = fsig(acc[1][r0 + 1]);
            float gv = ftanh(acc[2][r0 + 1]);
            float ov = fsig(acc[3][r0 + 1]);
            cc1 = fv * cc1 + iv * gv;
            float h = ov * ftanh(cc1);
            __bf16 hb = (__bf16)h;
            wbf[h_e1a] = hb;
            wbf[h_e1b] = hb;
            if (t == Tlen - 1) hlast[(brb + 1) * Hdim + hc] = h;
        }

        // stage x_{t+1} (held in xpre) into the write buffer, both copies
        if (sx_on && (t + 1) < Tlen) {
            __bf16 xa[2] = {(__bf16)xpre.x, (__bf16)xpre.y};
            *(uint*)&wbf[sx_e0] = *(uint*)xa;
            *(uint*)&wbf[sx_e1] = *(uint*)xa;
        }
        xpre = xnext;
        __syncthreads();   // the ONLY barrier per step
    }

    // ---- head: z = relu(h @ W1^T + b1); out = sigmoid(z @ W2^T + b2) ----
    if (tid < ROWS * 32) {
        const int b = tid >> 5, n = tid & 31;
        const float4* w4 = (const float4*)(W1 + n * Hdim);
        const float4* h4 = (const float4*)(hlast + b * Hdim);
        float s = b1[n];
        #pragma unroll
        for (int kk = 0; kk < Hdim / 4; ++kk) {
            float4 wv = w4[kk];
            float4 hv = h4[kk];
            s += wv.x * hv.x + wv.y * hv.y + wv.z * hv.z + wv.w * hv.w;
        }
        zbuf[b * 32 + n] = fmaxf(s, 0.0f);
    }
    __syncthreads();
    if (tid < ROWS) {
        float s = b2[0];
        #pragma unroll
        for (int n = 0; n < 32; ++n) s += zbuf[tid * 32 + n] * W2[n];
        out[b0 + tid] = fsig(s);
    }
}

extern "C" void kernel_launch(void* const* d_in, const int* in_sizes, int n_in,
                              void* d_out, int out_size, void* d_ws, size_t ws_size,
                              hipStream_t stream) {
    const float* x    = (const float*)d_in[0];
    const float* W_ih = (const float*)d_in[1];
    const float* W_hh = (const float*)d_in[2];
    const float* b_ih = (const float*)d_in[3];
    const float* b_hh = (const float*)d_in[4];
    const float* W1   = (const float*)d_in[5];
    const float* b1   = (const float*)d_in[6];
    const float* W2   = (const float*)d_in[7];
    const float* b2   = (const float*)d_in[8];
    float* out = (float*)d_out;

    dim3 grid(Bsz / ROWS), block(NTH);
    lstm_fused<<<grid, block, 0, stream>>>(x, W_ih, W_hh, b_ih, b_hh, W1, b1, W2, b2, out);
}